// Round 10
// baseline (361.872 us; speedup 1.0000x reference)
//
#include <hip/hip_runtime.h>

#define NN 100000
#define NE 3200000
#define FIN 128
#define HID 32
#define MH  64
#define NC  10
#define NG  64
#define NBKT 782           // ceil(NN/128) buckets of 128 dest nodes
#define NBLK 512           // edge-pass blocks
#define EPB  (NE / NBLK)   // 6250 edges per block
#define SCANL (NBKT * NBLK)
#define SRCMASK 0x1FFFF    // src < 100000 < 2^17
#define BCAP 5120          // bucket LDS capacity (mean 4092, sd ~64)

typedef float floatx2 __attribute__((ext_vector_type(2)));

// per-block LDS histogram over 782 dest-buckets; no global atomics
__global__ __launch_bounds__(1024)
void hist_bkt(const int* __restrict__ ei, int* __restrict__ cnt2) {
    __shared__ int h[NBKT];
    int tid = threadIdx.x, blk = blockIdx.x;
    for (int b = tid; b < NBKT; b += 1024) h[b] = 0;
    __syncthreads();
    int base = blk * EPB;
    for (int i = tid; i < EPB; i += 1024)
        atomicAdd(&h[ei[NE + base + i] >> 7], 1);
    __syncthreads();
    for (int b = tid; b < NBKT; b += 1024) cnt2[b * NBLK + blk] = h[b];
}

// ---- generic exclusive scan (1024 elems/block) ----
__global__ void scan_block(const int* __restrict__ in, int* __restrict__ out,
                           int* __restrict__ bsum, int n) {
    __shared__ int lds[256];
    int tid = threadIdx.x;
    int base = blockIdx.x * 1024 + tid * 4;
    int v0 = 0, v1 = 0, v2 = 0, v3 = 0;
    if (base + 0 < n) v0 = in[base + 0];
    if (base + 1 < n) v1 = in[base + 1];
    if (base + 2 < n) v2 = in[base + 2];
    if (base + 3 < n) v3 = in[base + 3];
    int s = v0 + v1 + v2 + v3;
    lds[tid] = s;
    __syncthreads();
    for (int off = 1; off < 256; off <<= 1) {
        int val = (tid >= off) ? lds[tid - off] : 0;
        __syncthreads();
        lds[tid] += val;
        __syncthreads();
    }
    int excl = lds[tid] - s;
    if (tid == 255) bsum[blockIdx.x] = lds[255];
    if (base + 0 < n) out[base + 0] = excl;
    if (base + 1 < n) out[base + 1] = excl + v0;
    if (base + 2 < n) out[base + 2] = excl + v0 + v1;
    if (base + 3 < n) out[base + 3] = excl + v0 + v1 + v2;
}

// wave-parallel exclusive scan of bsum; also zeroes pooled sums+counts
__global__ void scan_top(int* __restrict__ bsum, int nb, float* __restrict__ sc) {
    int lane = threadIdx.x;  // 64 threads
    for (int i = lane; i < NG * HID + NG; i += 64) sc[i] = 0.0f;
    int carry = 0;
    for (int base = 0; base < nb; base += 64) {
        int i = base + lane;
        int orig = (i < nb) ? bsum[i] : 0;
        int v = orig;
#pragma unroll
        for (int off = 1; off < 64; off <<= 1) {
            int t = __shfl_up(v, off, 64);
            if (lane >= off) v += t;
        }
        if (i < nb) bsum[i] = carry + v - orig;   // exclusive
        carry += __shfl(v, 63, 64);
    }
}

// single global read: pack each edge into LDS at its sorted slot, then
// slot-major burst writes to tre. bsum folded in (no scan_add pass).
__global__ __launch_bounds__(1024)
void scatter_bkt(const int* __restrict__ ei, const float* __restrict__ ew,
                 const int* __restrict__ cnt2, const int* __restrict__ scanned,
                 const int* __restrict__ bsum, int2* __restrict__ tre) {
    __shared__ int2 pay[EPB];      // 50 KB
    __shared__ int scur[NBKT];
    __shared__ int hexc[NBKT];
    __shared__ int gbase[NBKT];
    int tid = threadIdx.x, blk = blockIdx.x;
    int myh = 0;
    if (tid < NBKT) {
        int idx = tid * NBLK + blk;
        myh = cnt2[idx];
        gbase[tid] = scanned[idx] + bsum[idx >> 10];
        scur[tid] = myh;
    }
    __syncthreads();
    for (int off = 1; off < NBKT; off <<= 1) {
        int v = (tid < NBKT && tid >= off) ? scur[tid - off] : 0;
        __syncthreads();
        if (tid < NBKT) scur[tid] += v;
        __syncthreads();
    }
    if (tid < NBKT) { int ex = scur[tid] - myh; hexc[tid] = ex; scur[tid] = ex; }
    __syncthreads();
    int base = blk * EPB;
    for (int i = tid; i < EPB; i += 1024) {
        int e = base + i;
        int c = ei[NE + e];
        int r = ei[e];
        unsigned int wb = __float_as_uint(ew[e]);
        int b = c >> 7;
        int j = atomicAdd(&scur[b], 1);
        pay[j] = make_int2(r | ((c & 127) << 17) | ((b & 0xFF) << 24),
                           (int)((wb & ~3u) | ((unsigned)b >> 8)));
    }
    __syncthreads();
    for (int j = tid; j < EPB; j += 1024) {
        int2 q = pay[j];
        int b = (int)((((unsigned)q.y & 3u) << 8) | (((unsigned)q.x >> 24) & 0xFFu));
        int pos = gbase[b] + (j - hexc[b]);
        tre[pos] = make_int2(q.x & 0x00FFFFFF, q.y & ~3);
    }
}

// per bucket, lean: pass1 fuses stage+count+weighted-degree; wave-0 shuffle
// scan of 128 bins writes rowptr+dinv; pass2 emits node-sorted 4B edges.
// srn4 encoding (PROVEN): bits[16:0] = src node, bits[31:17] = bf16 weight
// bits[14:0] (positive). bsum folded in (no scan_add pass).
__global__ __launch_bounds__(512)
void sort_k(const int2* __restrict__ tre, const int* __restrict__ scanned,
            const int* __restrict__ bsum, unsigned int* __restrict__ srn4,
            int* __restrict__ rowptr, float* __restrict__ dinv) {
    __shared__ int2 ed[BCAP];      // 40 KB
    __shared__ int h[128];
    __shared__ float dw[128];
    __shared__ int cur[128];
    int b = blockIdx.x, tid = threadIdx.x;
    int base = scanned[b * NBLK] + bsum[(b * NBLK) >> 10];
    int end = (b == NBKT - 1)
                  ? NE
                  : scanned[(b + 1) * NBLK] + bsum[((b + 1) * NBLK) >> 10];
    int n = end - base;
    bool staged = (n <= BCAP);
    if (tid < 128) { h[tid] = 0; dw[tid] = 0.f; }
    __syncthreads();
    for (int i = tid; i < n; i += 512) {
        int2 q = tre[base + i];
        if (staged) ed[i] = q;
        int key = (q.x >> 17) & 127;
        atomicAdd(&h[key], 1);
        atomicAdd(&dw[key], __int_as_float(q.y));
    }
    __syncthreads();
    if (tid < 64) {
        int lane = tid;
        int carry = 0;
#pragma unroll
        for (int c = 0; c < 2; ++c) {
            int idx = c * 64 + lane;
            int hv = h[idx];
            int v = hv;
#pragma unroll
            for (int off = 1; off < 64; off <<= 1) {
                int t = __shfl_up(v, off, 64);
                if (lane >= off) v += t;
            }
            cur[idx] = base + carry + v - hv;           // start cursor
            int node = b * 128 + idx;
            if (node < NN) {
                rowptr[node] = base + carry + v;        // end offset
                dinv[node] = rsqrtf(1.0f + dw[idx]);    // self-loop included
            }
            carry += __shfl(v, 63, 64);
        }
    }
    __syncthreads();
    for (int i = tid; i < n; i += 512) {
        int2 q = staged ? ed[i] : tre[base + i];
        int key = (q.x >> 17) & 127;
        int pos = atomicAdd(&cur[key], 1);
        unsigned int wb = (unsigned)q.y;                // positive ew bits
        wb += 0x7FFFu + ((wb >> 16) & 1u);              // RNE to bf16
        srn4[pos] = (unsigned)(q.x & SRCMASK) | (((wb >> 16) & 0x7FFFu) << 17);
    }
}

// LDS-tiled linear (layer 1 only): 64-row x tile; W pre-swizzled; thread =
// 2 rows x 4 contiguous cols; output = fp8(dinv[row] * acc).
template <int IN_DIM, bool RELU_IN>
__global__ __launch_bounds__(256)
void linear_k(const float* __restrict__ in, const float* __restrict__ W,
              const float* __restrict__ dinv, unsigned int* __restrict__ tmp8) {
    constexpr int J4 = IN_DIM / 4;
    constexpr int XSS = J4 + 1;
    __shared__ float4 xs[64 * XSS];
    __shared__ float4 wp[IN_DIM * 8];
    int tid = threadIdx.x;
    for (int idx = tid; idx < IN_DIM * 8; idx += 256) {
        int j = idx >> 3, kg = idx & 7;
        const float* wr = W + j * 32 + kg * 4;
        wp[idx] = make_float4(wr[0], wr[1], wr[2], wr[3]);
    }
    int rbase = blockIdx.x * 64;
    const float4* in4 = (const float4*)in;
    for (int idx = tid; idx < 64 * J4; idx += 256) {
        int row = idx / J4, j4 = idx % J4;
        int grow = rbase + row;
        float4 v = (grow < NN) ? in4[(size_t)grow * J4 + j4]
                               : make_float4(0.f, 0.f, 0.f, 0.f);
        if (RELU_IN) {
            v.x = fmaxf(v.x, 0.f); v.y = fmaxf(v.y, 0.f);
            v.z = fmaxf(v.z, 0.f); v.w = fmaxf(v.w, 0.f);
        }
        xs[row * XSS + j4] = v;
    }
    __syncthreads();
    int kg = tid & 7;
    int rp = tid >> 3;
    int r0 = rbase + 2 * rp;
    if (r0 >= NN) return;
    const float4* x0 = &xs[(2 * rp) * XSS];
    const float4* x1 = &xs[(2 * rp + 1) * XSS];
    float a00 = 0, a01 = 0, a02 = 0, a03 = 0;
    float a10 = 0, a11 = 0, a12 = 0, a13 = 0;
#pragma unroll
    for (int j4 = 0; j4 < J4; ++j4) {
        float4 v0 = x0[j4], v1 = x1[j4];
        const float4* wj = &wp[j4 * 4 * 8 + kg];
        float4 w0 = wj[0], w1 = wj[8], w2 = wj[16], w3 = wj[24];
#define LSTEP(VX0, VX1, W4) \
        a00 = fmaf(VX0, W4.x, a00); a01 = fmaf(VX0, W4.y, a01); \
        a02 = fmaf(VX0, W4.z, a02); a03 = fmaf(VX0, W4.w, a03); \
        a10 = fmaf(VX1, W4.x, a10); a11 = fmaf(VX1, W4.y, a11); \
        a12 = fmaf(VX1, W4.z, a12); a13 = fmaf(VX1, W4.w, a13);
        LSTEP(v0.x, v1.x, w0)
        LSTEP(v0.y, v1.y, w1)
        LSTEP(v0.z, v1.z, w2)
        LSTEP(v0.w, v1.w, w3)
#undef LSTEP
    }
    float d0 = dinv[r0], d1 = dinv[r0 + 1];
    a00 *= d0; a01 *= d0; a02 *= d0; a03 *= d0;
    a10 *= d1; a11 *= d1; a12 *= d1; a13 *= d1;
    int q0 = __builtin_amdgcn_cvt_pk_fp8_f32(a00, a01, 0, false);
    q0 = __builtin_amdgcn_cvt_pk_fp8_f32(a02, a03, q0, true);
    int q1 = __builtin_amdgcn_cvt_pk_fp8_f32(a10, a11, 0, false);
    q1 = __builtin_amdgcn_cvt_pk_fp8_f32(a12, a13, q1, true);
    tmp8[r0 * 8 + kg] = (unsigned int)q0;
    tmp8[(r0 + 1) * 8 + kg] = (unsigned int)q1;
}

// gather core v5: EIGHT nodes per wave, one lane per edge (full 32B row via
// 2x dwordx4), masked burst of 4. lane = n*8 + s. 256 edges in flight per
// wave; reduce/epilogue overhead amortized over 8 nodes. After the 3-level
// xor-butterfly (masks 1,2,4) EVERY lane of a node group holds the full
// 32-feature sum in registers.
struct AccR {
    floatx2 r0, r1, r2, r3, r4, r5, r6, r7;
    floatx2 r8, r9, r10, r11, r12, r13, r14, r15;
};

#define ACC16(UL, UH, W) { \
    floatx2 lo_, hi_; \
    lo_ = __builtin_amdgcn_cvt_pk_f32_fp8(UL.x, false); \
    hi_ = __builtin_amdgcn_cvt_pk_f32_fp8(UL.x, true); \
    a0 += lo_ * W; a1 += hi_ * W; \
    lo_ = __builtin_amdgcn_cvt_pk_f32_fp8(UL.y, false); \
    hi_ = __builtin_amdgcn_cvt_pk_f32_fp8(UL.y, true); \
    a2 += lo_ * W; a3 += hi_ * W; \
    lo_ = __builtin_amdgcn_cvt_pk_f32_fp8(UL.z, false); \
    hi_ = __builtin_amdgcn_cvt_pk_f32_fp8(UL.z, true); \
    a4 += lo_ * W; a5 += hi_ * W; \
    lo_ = __builtin_amdgcn_cvt_pk_f32_fp8(UL.w, false); \
    hi_ = __builtin_amdgcn_cvt_pk_f32_fp8(UL.w, true); \
    a6 += lo_ * W; a7 += hi_ * W; \
    lo_ = __builtin_amdgcn_cvt_pk_f32_fp8(UH.x, false); \
    hi_ = __builtin_amdgcn_cvt_pk_f32_fp8(UH.x, true); \
    a8 += lo_ * W; a9 += hi_ * W; \
    lo_ = __builtin_amdgcn_cvt_pk_f32_fp8(UH.y, false); \
    hi_ = __builtin_amdgcn_cvt_pk_f32_fp8(UH.y, true); \
    a10 += lo_ * W; a11 += hi_ * W; \
    lo_ = __builtin_amdgcn_cvt_pk_f32_fp8(UH.z, false); \
    hi_ = __builtin_amdgcn_cvt_pk_f32_fp8(UH.z, true); \
    a12 += lo_ * W; a13 += hi_ * W; \
    lo_ = __builtin_amdgcn_cvt_pk_f32_fp8(UH.w, false); \
    hi_ = __builtin_amdgcn_cvt_pk_f32_fp8(UH.w, true); \
    a14 += lo_ * W; a15 += hi_ * W; }

__device__ __forceinline__ AccR agg_core(const unsigned int* __restrict__ srn4,
                                         const int* __restrict__ rowptr,
                                         const unsigned int* __restrict__ tmp8,
                                         int nid, int s) {
    const char* t8 = (const char*)tmp8;
    int end = rowptr[nid];
    int start = (nid == 0) ? 0 : rowptr[nid - 1];
    floatx2 a0 = {0.f,0.f}, a1 = {0.f,0.f}, a2 = {0.f,0.f}, a3 = {0.f,0.f};
    floatx2 a4 = {0.f,0.f}, a5 = {0.f,0.f}, a6 = {0.f,0.f}, a7 = {0.f,0.f};
    floatx2 a8 = {0.f,0.f}, a9 = {0.f,0.f}, a10 = {0.f,0.f}, a11 = {0.f,0.f};
    floatx2 a12 = {0.f,0.f}, a13 = {0.f,0.f}, a14 = {0.f,0.f}, a15 = {0.f,0.f};
    int eM = end - 1;
    for (int e = start + s; e < end; e += 32) {
        int i1 = min(e + 8, eM);
        int i2 = min(e + 16, eM);
        int i3 = min(e + 24, eM);
        unsigned int p0 = srn4[e];
        unsigned int p1 = srn4[i1];
        unsigned int p2 = srn4[i2];
        unsigned int p3 = srn4[i3];
        const char* r0p = t8 + ((p0 & SRCMASK) << 5);
        const char* r1p = t8 + ((p1 & SRCMASK) << 5);
        const char* r2p = t8 + ((p2 & SRCMASK) << 5);
        const char* r3p = t8 + ((p3 & SRCMASK) << 5);
        uint4 uL0 = *(const uint4*)r0p, uH0 = *(const uint4*)(r0p + 16);
        uint4 uL1 = *(const uint4*)r1p, uH1 = *(const uint4*)(r1p + 16);
        uint4 uL2 = *(const uint4*)r2p, uH2 = *(const uint4*)(r2p + 16);
        uint4 uL3 = *(const uint4*)r3p, uH3 = *(const uint4*)(r3p + 16);
        float w0 = __uint_as_float((p0 >> 1) & 0x7FFF0000u);
        float w1 = (e + 8  <= eM) ? __uint_as_float((p1 >> 1) & 0x7FFF0000u) : 0.f;
        float w2 = (e + 16 <= eM) ? __uint_as_float((p2 >> 1) & 0x7FFF0000u) : 0.f;
        float w3 = (e + 24 <= eM) ? __uint_as_float((p3 >> 1) & 0x7FFF0000u) : 0.f;
        ACC16(uL0, uH0, w0)
        ACC16(uL1, uH1, w1)
        ACC16(uL2, uH2, w2)
        ACC16(uL3, uH3, w3)
    }
    // reduce across the 8 slots: lane bits 0..2 (masks 1,2,4)
#define REDM(M) { \
    a0.x += __shfl_xor(a0.x, M, 64);  a0.y += __shfl_xor(a0.y, M, 64); \
    a1.x += __shfl_xor(a1.x, M, 64);  a1.y += __shfl_xor(a1.y, M, 64); \
    a2.x += __shfl_xor(a2.x, M, 64);  a2.y += __shfl_xor(a2.y, M, 64); \
    a3.x += __shfl_xor(a3.x, M, 64);  a3.y += __shfl_xor(a3.y, M, 64); \
    a4.x += __shfl_xor(a4.x, M, 64);  a4.y += __shfl_xor(a4.y, M, 64); \
    a5.x += __shfl_xor(a5.x, M, 64);  a5.y += __shfl_xor(a5.y, M, 64); \
    a6.x += __shfl_xor(a6.x, M, 64);  a6.y += __shfl_xor(a6.y, M, 64); \
    a7.x += __shfl_xor(a7.x, M, 64);  a7.y += __shfl_xor(a7.y, M, 64); \
    a8.x += __shfl_xor(a8.x, M, 64);  a8.y += __shfl_xor(a8.y, M, 64); \
    a9.x += __shfl_xor(a9.x, M, 64);  a9.y += __shfl_xor(a9.y, M, 64); \
    a10.x += __shfl_xor(a10.x, M, 64); a10.y += __shfl_xor(a10.y, M, 64); \
    a11.x += __shfl_xor(a11.x, M, 64); a11.y += __shfl_xor(a11.y, M, 64); \
    a12.x += __shfl_xor(a12.x, M, 64); a12.y += __shfl_xor(a12.y, M, 64); \
    a13.x += __shfl_xor(a13.x, M, 64); a13.y += __shfl_xor(a13.y, M, 64); \
    a14.x += __shfl_xor(a14.x, M, 64); a14.y += __shfl_xor(a14.y, M, 64); \
    a15.x += __shfl_xor(a15.x, M, 64); a15.y += __shfl_xor(a15.y, M, 64); }
    REDM(1) REDM(2) REDM(4)
#undef REDM
    AccR r;
    r.r0 = a0;  r.r1 = a1;  r.r2 = a2;  r.r3 = a3;
    r.r4 = a4;  r.r5 = a5;  r.r6 = a6;  r.r7 = a7;
    r.r8 = a8;  r.r9 = a9;  r.r10 = a10; r.r11 = a11;
    r.r12 = a12; r.r13 = a13; r.r14 = a14; r.r15 = a15;
    return r;
}

// 16-feature epilogue from 8 floatx2 partials + self-value uint4 + bias ptr.
#define EPI16(O0,O1,O2,O3, R0,R1,R2,R3,R4,R5,R6,R7, SV, BP, D, RELU) { \
    floatx2 s0_ = __builtin_amdgcn_cvt_pk_f32_fp8(SV.x, false); \
    floatx2 s1_ = __builtin_amdgcn_cvt_pk_f32_fp8(SV.x, true); \
    floatx2 s2_ = __builtin_amdgcn_cvt_pk_f32_fp8(SV.y, false); \
    floatx2 s3_ = __builtin_amdgcn_cvt_pk_f32_fp8(SV.y, true); \
    floatx2 s4_ = __builtin_amdgcn_cvt_pk_f32_fp8(SV.z, false); \
    floatx2 s5_ = __builtin_amdgcn_cvt_pk_f32_fp8(SV.z, true); \
    floatx2 s6_ = __builtin_amdgcn_cvt_pk_f32_fp8(SV.w, false); \
    floatx2 s7_ = __builtin_amdgcn_cvt_pk_f32_fp8(SV.w, true); \
    float4 b0_ = BP[0], b1_ = BP[1], b2_ = BP[2], b3_ = BP[3]; \
    O0.x = b0_.x + (D) * (s0_.x + R0.x); \
    O0.y = b0_.y + (D) * (s0_.y + R0.y); \
    O0.z = b0_.z + (D) * (s1_.x + R1.x); \
    O0.w = b0_.w + (D) * (s1_.y + R1.y); \
    O1.x = b1_.x + (D) * (s2_.x + R2.x); \
    O1.y = b1_.y + (D) * (s2_.y + R2.y); \
    O1.z = b1_.z + (D) * (s3_.x + R3.x); \
    O1.w = b1_.w + (D) * (s3_.y + R3.y); \
    O2.x = b2_.x + (D) * (s4_.x + R4.x); \
    O2.y = b2_.y + (D) * (s4_.y + R4.y); \
    O2.z = b2_.z + (D) * (s5_.x + R5.x); \
    O2.w = b2_.w + (D) * (s5_.y + R5.y); \
    O3.x = b3_.x + (D) * (s6_.x + R6.x); \
    O3.y = b3_.y + (D) * (s6_.y + R6.y); \
    O3.z = b3_.z + (D) * (s7_.x + R7.x); \
    O3.w = b3_.w + (D) * (s7_.y + R7.y); \
    if (RELU) { \
        O0.x = fmaxf(O0.x, 0.f); O0.y = fmaxf(O0.y, 0.f); \
        O0.z = fmaxf(O0.z, 0.f); O0.w = fmaxf(O0.w, 0.f); \
        O1.x = fmaxf(O1.x, 0.f); O1.y = fmaxf(O1.y, 0.f); \
        O1.z = fmaxf(O1.z, 0.f); O1.w = fmaxf(O1.w, 0.f); \
        O2.x = fmaxf(O2.x, 0.f); O2.y = fmaxf(O2.y, 0.f); \
        O2.z = fmaxf(O2.z, 0.f); O2.w = fmaxf(O2.w, 0.f); \
        O3.x = fmaxf(O3.x, 0.f); O3.y = fmaxf(O3.y, 0.f); \
        O3.z = fmaxf(O3.z, 0.f); O3.w = fmaxf(O3.w, 0.f); \
    } }

// plain aggregate (layer 3): writes fp32 h for pooling (no relu).
// 8 nodes per wave: 3125 blocks x 32 nodes. No barrier.
__global__ __launch_bounds__(256)
void aggregate(const unsigned int* __restrict__ srn4,
               const int* __restrict__ rowptr,
               const float* __restrict__ dinv,
               const float* __restrict__ bias,
               const unsigned int* __restrict__ tmp8,
               float* __restrict__ h) {
    int tid = threadIdx.x;
    int nid = (blockIdx.x * 256 + tid) >> 3;   // 3125*32 == NN exactly
    int lane = tid & 63;
    int s = lane & 7;
    AccR A = agg_core(srn4, rowptr, tmp8, nid, s);
    if (s < 2) {                               // 2 lanes per node, 16 feats each
        const char* t8 = (const char*)tmp8;
        float d = dinv[nid];
        uint4 sv = *(const uint4*)(t8 + (((unsigned)nid) << 5) + 16 * s);
        const float4* bp = (const float4*)bias + 4 * s;
        float4 o0, o1, o2, o3;
        if (s == 0) {
            EPI16(o0, o1, o2, o3, A.r0, A.r1, A.r2, A.r3, A.r4, A.r5, A.r6, A.r7,
                  sv, bp, d, false)
        } else {
            EPI16(o0, o1, o2, o3, A.r8, A.r9, A.r10, A.r11, A.r12, A.r13, A.r14,
                  A.r15, sv, bp, d, false)
        }
        float4* hp = (float4*)(h + (size_t)nid * HID + 16 * s);
        hp[0] = o0; hp[1] = o1; hp[2] = o2; hp[3] = o3;
    }
}

// fused aggregate + relu + 32x32 next-layer linear + fp8 store (layers 1->2,
// 2->3). 8 nodes per wave; every lane holds the full reduced row in regs, so
// the epilogue is computed in-register (no hrow LDS, no staging hazard) and
// each lane computes 4 matvec outputs (j0, j0+8, j0+16, j0+24) with Wt rows
// read broadcast from LDS.
__global__ __launch_bounds__(256)
void agg_lin(const unsigned int* __restrict__ srn4,
             const int* __restrict__ rowptr,
             const float* __restrict__ dinv,
             const float* __restrict__ bias,
             const float* __restrict__ Wn,
             const unsigned int* __restrict__ tmp8,
             unsigned int* __restrict__ tmp8_out) {
    __shared__ float Wt[32][36];               // 4.6 KB, transposed W
    int tid = threadIdx.x;
    for (int idx = tid; idx < 1024; idx += 256)
        Wt[idx & 31][idx >> 5] = Wn[idx];      // Wt[j][k] = Wn[k*32+j]
    int nid = (blockIdx.x * 256 + tid) >> 3;   // 3125*32 == NN exactly
    int lane = tid & 63;
    int s = lane & 7;
    __syncthreads();                           // Wt ready (uniform)
    AccR A = agg_core(srn4, rowptr, tmp8, nid, s);
    float d = dinv[nid];
    const char* t8 = (const char*)tmp8;
    uint4 svL = *(const uint4*)(t8 + (((unsigned)nid) << 5));
    uint4 svH = *(const uint4*)(t8 + (((unsigned)nid) << 5) + 16);
    const float4* bl = (const float4*)bias;
    float4 h0, h1, h2, h3, h4, h5, h6, h7;
    EPI16(h0, h1, h2, h3, A.r0, A.r1, A.r2, A.r3, A.r4, A.r5, A.r6, A.r7,
          svL, bl, d, true)
    EPI16(h4, h5, h6, h7, A.r8, A.r9, A.r10, A.r11, A.r12, A.r13, A.r14, A.r15,
          svH, (bl + 4), d, true)
    // matvec: lane computes outputs j0, j0+8, j0+16, j0+24 (full 32-k dots)
    int j0 = s;
    const float4* wr0 = (const float4*)&Wt[j0][0];
    const float4* wr1 = (const float4*)&Wt[j0 + 8][0];
    const float4* wr2 = (const float4*)&Wt[j0 + 16][0];
    const float4* wr3 = (const float4*)&Wt[j0 + 24][0];
    float y0 = 0.f, y1 = 0.f, y2 = 0.f, y3 = 0.f;
#define MV(K, HV) { \
    float4 wa_ = wr0[K], wb_ = wr1[K], wc_ = wr2[K], wd_ = wr3[K]; \
    y0 = fmaf(HV.x, wa_.x, y0); y0 = fmaf(HV.y, wa_.y, y0); \
    y0 = fmaf(HV.z, wa_.z, y0); y0 = fmaf(HV.w, wa_.w, y0); \
    y1 = fmaf(HV.x, wb_.x, y1); y1 = fmaf(HV.y, wb_.y, y1); \
    y1 = fmaf(HV.z, wb_.z, y1); y1 = fmaf(HV.w, wb_.w, y1); \
    y2 = fmaf(HV.x, wc_.x, y2); y2 = fmaf(HV.y, wc_.y, y2); \
    y2 = fmaf(HV.z, wc_.z, y2); y2 = fmaf(HV.w, wc_.w, y2); \
    y3 = fmaf(HV.x, wd_.x, y3); y3 = fmaf(HV.y, wd_.y, y3); \
    y3 = fmaf(HV.z, wd_.z, y3); y3 = fmaf(HV.w, wd_.w, y3); }
    MV(0, h0) MV(1, h1) MV(2, h2) MV(3, h3)
    MV(4, h4) MV(5, h5) MV(6, h6) MV(7, h7)
#undef MV
    y0 *= d; y1 *= d; y2 *= d; y3 *= d;
    // pack quads: feat f owned by lane (f&7) at output slot (f>>3); quad t
    // spans 4 consecutive lanes starting at (4t)&7 (0 or 4), all in-group.
    float p01 = __shfl_down(y0, 1, 64), p02 = __shfl_down(y0, 2, 64),
          p03 = __shfl_down(y0, 3, 64);
    float p11 = __shfl_down(y1, 1, 64), p12 = __shfl_down(y1, 2, 64),
          p13 = __shfl_down(y1, 3, 64);
    float p21 = __shfl_down(y2, 1, 64), p22 = __shfl_down(y2, 2, 64),
          p23 = __shfl_down(y2, 3, 64);
    float p31 = __shfl_down(y3, 1, 64), p32 = __shfl_down(y3, 2, 64),
          p33 = __shfl_down(y3, 3, 64);
    if ((s & 3) == 0) {                        // lanes s=0 (even quads), s=4 (odd)
        int bb = nid * 8 + (s >> 2);
        int q0 = __builtin_amdgcn_cvt_pk_fp8_f32(y0, p01, 0, false);
        q0 = __builtin_amdgcn_cvt_pk_fp8_f32(p02, p03, q0, true);
        int q1 = __builtin_amdgcn_cvt_pk_fp8_f32(y1, p11, 0, false);
        q1 = __builtin_amdgcn_cvt_pk_fp8_f32(p12, p13, q1, true);
        int q2 = __builtin_amdgcn_cvt_pk_fp8_f32(y2, p21, 0, false);
        q2 = __builtin_amdgcn_cvt_pk_fp8_f32(p22, p23, q2, true);
        int q3 = __builtin_amdgcn_cvt_pk_fp8_f32(y3, p31, 0, false);
        q3 = __builtin_amdgcn_cvt_pk_fp8_f32(p32, p33, q3, true);
        tmp8_out[bb + 0] = (unsigned int)q0;
        tmp8_out[bb + 2] = (unsigned int)q1;
        tmp8_out[bb + 4] = (unsigned int)q2;
        tmp8_out[bb + 6] = (unsigned int)q3;
    }
}

// sorted-batch run-length pooling (3125 chunks x 32 nodes, boundary atomics)
__global__ void pool_k(const float* __restrict__ h, const int* __restrict__ batch,
                       float* __restrict__ sums, float* __restrict__ counts) {
    int t = blockIdx.x * 256 + threadIdx.x;
    int chunk = t >> 5, k = t & 31;
    int n0 = chunk * 32;
    if (n0 >= NN) return;
    int n1 = min(n0 + 32, NN);
    int g = batch[n0];
    float acc = 0.f, cacc = 0.f;
    for (int i = n0; i < n1; ++i) {
        int gi = batch[i];
        if (gi != g) {
            atomicAdd(&sums[g * HID + k], acc);
            if (k == 0) atomicAdd(&counts[g], cacc);
            g = gi; acc = 0.f; cacc = 0.f;
        }
        acc += h[(size_t)i * HID + k];
        cacc += 1.f;
    }
    atomicAdd(&sums[g * HID + k], acc);
    if (k == 0) atomicAdd(&counts[g], cacc);
}

// MLP: one block per graph, one wave; thread k owns output column k.
__global__ __launch_bounds__(64)
void mlp_k(const float* __restrict__ sums, const float* __restrict__ counts,
           const float* __restrict__ Wm0, const float* __restrict__ bm0,
           const float* __restrict__ Wm1, const float* __restrict__ bm1,
           const float* __restrict__ Wout, const float* __restrict__ bout,
           float* __restrict__ out) {
    __shared__ float g0[HID];
    __shared__ float g1[MH];
    __shared__ float g2[MH];
    int g = blockIdx.x;
    int k = threadIdx.x;
    if (k < HID) g0[k] = sums[g * HID + k] / fmaxf(counts[g], 1.0f);
    __syncthreads();
    float acc = bm0[k];
#pragma unroll
    for (int j = 0; j < HID; ++j) acc = fmaf(g0[j], Wm0[j * MH + k], acc);
    g1[k] = fmaxf(acc, 0.f);
    __syncthreads();
    float acc2 = bm1[k];
#pragma unroll
    for (int j = 0; j < MH; ++j) acc2 = fmaf(g1[j], Wm1[j * MH + k], acc2);
    g2[k] = fmaxf(acc2, 0.f);
    __syncthreads();
    if (k < NC) {
        float acc3 = bout[k];
#pragma unroll
        for (int j = 0; j < MH; ++j) acc3 = fmaf(g2[j], Wout[j * NC + k], acc3);
        out[g * NC + k] = acc3;
    }
}

extern "C" void kernel_launch(void* const* d_in, const int* in_sizes, int n_in,
                              void* d_out, int out_size, void* d_ws, size_t ws_size,
                              hipStream_t stream) {
    const float* x    = (const float*)d_in[0];
    const int*   ei   = (const int*)d_in[1];
    const float* ew   = (const float*)d_in[2];
    const int*   batch= (const int*)d_in[3];
    const float* W1   = (const float*)d_in[4];
    const float* b1   = (const float*)d_in[5];
    const float* W2   = (const float*)d_in[6];
    const float* b2   = (const float*)d_in[7];
    const float* W3   = (const float*)d_in[8];
    const float* b3   = (const float*)d_in[9];
    const float* Wm0  = (const float*)d_in[10];
    const float* bm0  = (const float*)d_in[11];
    const float* Wm1  = (const float*)d_in[12];
    const float* bm1  = (const float*)d_in[13];
    const float* Wout = (const float*)d_in[14];
    const float* bout = (const float*)d_in[15];
    float* out = (float*)d_out;

    // workspace: srn4 | S (tre+cnt2+scanned <-> tmp8+tmp8b+hA) | small bufs
    char* p = (char*)d_ws;
    unsigned int* srn4 = (unsigned int*)p; p += sizeof(unsigned int) * (size_t)NE; // 12.8 MB
    char*  S   = p;                      p += 12 * (size_t)NE;                // 38.4 MB shared
    int2*  tre = (int2*)S;                                                    // 25.6 MB
    int*   cnt2    = (int*)(S + sizeof(int2) * (size_t)NE);                   // 1.6 MB (dies pre-layer1)
    int*   scanned = cnt2 + SCANL;                                            // 1.6 MB
    unsigned int* tmp8  = (unsigned int*)S;                                   // 3.2 MB
    unsigned int* tmp8b = tmp8 + (size_t)NN * 8;                              // 3.2 MB
    float* hA  = (float*)(S + 2 * (size_t)NN * HID);                          // 12.8 MB
    int*   bsum    = (int*)p;            p += sizeof(int) * 512;
    float* dinv    = (float*)p;          p += sizeof(float) * NN;
    int*   rowptr  = (int*)p;            p += sizeof(int) * NN;
    float* sums    = (float*)p;          p += sizeof(float) * NG * HID;
    float* counts  = (float*)p;

    dim3 blk(256);
    const int NB_SCAN = (SCANL + 1023) / 1024;  // 391
    const int NB_LIN = (NN + 63) / 64;          // 1563
    const int NB_AGG = 3125;                    // 32 nodes per block (8/wave)

    hist_bkt<<<NBLK, 1024, 0, stream>>>(ei, cnt2);
    scan_block<<<NB_SCAN, blk, 0, stream>>>(cnt2, scanned, bsum, SCANL);
    scan_top<<<1, 64, 0, stream>>>(bsum, NB_SCAN, sums);  // also zeroes sums+counts
    scatter_bkt<<<NBLK, 1024, 0, stream>>>(ei, ew, cnt2, scanned, bsum, tre);
    sort_k<<<NBKT, 512, 0, stream>>>(tre, scanned, bsum, srn4, rowptr, dinv);

    // layer 1 linear, then fused agg1+linear2, fused agg2+linear3, plain agg3
    linear_k<FIN, false><<<NB_LIN, blk, 0, stream>>>(x, W1, dinv, tmp8);
    agg_lin<<<NB_AGG, blk, 0, stream>>>(srn4, rowptr, dinv, b1, W2, tmp8, tmp8b);
    agg_lin<<<NB_AGG, blk, 0, stream>>>(srn4, rowptr, dinv, b2, W3, tmp8b, tmp8);
    aggregate<<<NB_AGG, blk, 0, stream>>>(srn4, rowptr, dinv, b3, tmp8, hA);

    pool_k<<<391, blk, 0, stream>>>(hA, batch, sums, counts);
    mlp_k<<<NG, 64, 0, stream>>>(sums, counts, Wm0, bm0, Wm1, bm1, Wout, bout, out);
}

// Round 11
// 355.352 us; speedup vs baseline: 1.0183x; 1.0183x over previous
//
#include <hip/hip_runtime.h>

#define NN 100000
#define NE 3200000
#define FIN 128
#define HID 32
#define MH  64
#define NC  10
#define NG  64
#define NBKT 782           // ceil(NN/128) buckets of 128 dest nodes
#define NBLK 512           // edge-pass blocks
#define EPB  (NE / NBLK)   // 6250 edges per block
#define SCANL (NBKT * NBLK)
#define SRCMASK 0x1FFFF    // src < 100000 < 2^17
#define BCAP 5120          // bucket LDS capacity (mean 4092, sd ~64)

typedef float floatx2 __attribute__((ext_vector_type(2)));

// per-block LDS histogram over 782 dest-buckets; cnt2 stored BLOCK-major
// (cnt2[blk*NBKT+b]) so the 782 stores per block are coalesced (the old
// bucket-major layout was 400K stride-2KB 4B stores = 1 line each).
__global__ __launch_bounds__(1024)
void hist_bkt(const int* __restrict__ ei, int* __restrict__ cnt2) {
    __shared__ int h[NBKT];
    int tid = threadIdx.x, blk = blockIdx.x;
    for (int b = tid; b < NBKT; b += 1024) h[b] = 0;
    __syncthreads();
    int base = blk * EPB;
    for (int i = tid; i < EPB; i += 1024)
        atomicAdd(&h[ei[NE + base + i] >> 7], 1);
    __syncthreads();
    for (int b = tid; b < NBKT; b += 1024) cnt2[blk * NBKT + b] = h[b];
}

// exclusive scan over the BUCKET-major sequence, reading block-major cnt2
// via index transform (scattered 4B reads, L2-resident 1.6MB => cheap).
// out (scanned) is written bucket-major, coalesced.
__global__ void scan_cnt(const int* __restrict__ cnt2, int* __restrict__ out,
                         int* __restrict__ bsum) {
    __shared__ int lds[256];
    int tid = threadIdx.x;
    int base = blockIdx.x * 1024 + tid * 4;    // 391*1024 == SCANL exactly
    int g0 = base, g1 = base + 1, g2 = base + 2, g3 = base + 3;
    int v0 = cnt2[(g0 & (NBLK - 1)) * NBKT + (g0 >> 9)];
    int v1 = cnt2[(g1 & (NBLK - 1)) * NBKT + (g1 >> 9)];
    int v2 = cnt2[(g2 & (NBLK - 1)) * NBKT + (g2 >> 9)];
    int v3 = cnt2[(g3 & (NBLK - 1)) * NBKT + (g3 >> 9)];
    int s = v0 + v1 + v2 + v3;
    lds[tid] = s;
    __syncthreads();
    for (int off = 1; off < 256; off <<= 1) {
        int val = (tid >= off) ? lds[tid - off] : 0;
        __syncthreads();
        lds[tid] += val;
        __syncthreads();
    }
    int excl = lds[tid] - s;
    if (tid == 255) bsum[blockIdx.x] = lds[255];
    out[base + 0] = excl;
    out[base + 1] = excl + v0;
    out[base + 2] = excl + v0 + v1;
    out[base + 3] = excl + v0 + v1 + v2;
}

// wave-parallel exclusive scan of bsum; also zeroes pooled sums+counts
__global__ void scan_top(int* __restrict__ bsum, int nb, float* __restrict__ sc) {
    int lane = threadIdx.x;  // 64 threads
    for (int i = lane; i < NG * HID + NG; i += 64) sc[i] = 0.0f;
    int carry = 0;
    for (int base = 0; base < nb; base += 64) {
        int i = base + lane;
        int orig = (i < nb) ? bsum[i] : 0;
        int v = orig;
#pragma unroll
        for (int off = 1; off < 64; off <<= 1) {
            int t = __shfl_up(v, off, 64);
            if (lane >= off) v += t;
        }
        if (i < nb) bsum[i] = carry + v - orig;   // exclusive
        carry += __shfl(v, 63, 64);
    }
}

// single global read: pack each edge into LDS at its sorted slot, then
// slot-major burst writes to tre. cnt2 read coalesced (block-major);
// scanned read scattered (L2-hit). bsum folded in (no scan_add pass).
__global__ __launch_bounds__(1024)
void scatter_bkt(const int* __restrict__ ei, const float* __restrict__ ew,
                 const int* __restrict__ cnt2, const int* __restrict__ scanned,
                 const int* __restrict__ bsum, int2* __restrict__ tre) {
    __shared__ int2 pay[EPB];      // 50 KB
    __shared__ int scur[NBKT];
    __shared__ int hexc[NBKT];
    __shared__ int gbase[NBKT];
    int tid = threadIdx.x, blk = blockIdx.x;
    int myh = 0;
    if (tid < NBKT) {
        int idx = tid * NBLK + blk;
        myh = cnt2[blk * NBKT + tid];
        gbase[tid] = scanned[idx] + bsum[idx >> 10];
        scur[tid] = myh;
    }
    __syncthreads();
    for (int off = 1; off < NBKT; off <<= 1) {
        int v = (tid < NBKT && tid >= off) ? scur[tid - off] : 0;
        __syncthreads();
        if (tid < NBKT) scur[tid] += v;
        __syncthreads();
    }
    if (tid < NBKT) { int ex = scur[tid] - myh; hexc[tid] = ex; scur[tid] = ex; }
    __syncthreads();
    int base = blk * EPB;
    for (int i = tid; i < EPB; i += 1024) {
        int e = base + i;
        int c = ei[NE + e];
        int r = ei[e];
        unsigned int wb = __float_as_uint(ew[e]);
        int b = c >> 7;
        int j = atomicAdd(&scur[b], 1);
        pay[j] = make_int2(r | ((c & 127) << 17) | ((b & 0xFF) << 24),
                           (int)((wb & ~3u) | ((unsigned)b >> 8)));
    }
    __syncthreads();
    for (int j = tid; j < EPB; j += 1024) {
        int2 q = pay[j];
        int b = (int)((((unsigned)q.y & 3u) << 8) | (((unsigned)q.x >> 24) & 0xFFu));
        int pos = gbase[b] + (j - hexc[b]);
        tre[pos] = make_int2(q.x & 0x00FFFFFF, q.y & ~3);
    }
}

// per bucket, lean: pass1 fuses stage+count+weighted-degree; wave-0 shuffle
// scan of 128 bins writes rowptr+dinv; pass2 emits node-sorted 4B edges.
// srn4 encoding (PROVEN): bits[16:0] = src node, bits[31:17] = bf16 weight
// bits[14:0] (positive). bsum folded in (no scan_add pass).
__global__ __launch_bounds__(512)
void sort_k(const int2* __restrict__ tre, const int* __restrict__ scanned,
            const int* __restrict__ bsum, unsigned int* __restrict__ srn4,
            int* __restrict__ rowptr, float* __restrict__ dinv) {
    __shared__ int2 ed[BCAP];      // 40 KB
    __shared__ int h[128];
    __shared__ float dw[128];
    __shared__ int cur[128];
    int b = blockIdx.x, tid = threadIdx.x;
    int base = scanned[b * NBLK] + bsum[(b * NBLK) >> 10];
    int end = (b == NBKT - 1)
                  ? NE
                  : scanned[(b + 1) * NBLK] + bsum[((b + 1) * NBLK) >> 10];
    int n = end - base;
    bool staged = (n <= BCAP);
    if (tid < 128) { h[tid] = 0; dw[tid] = 0.f; }
    __syncthreads();
    for (int i = tid; i < n; i += 512) {
        int2 q = tre[base + i];
        if (staged) ed[i] = q;
        int key = (q.x >> 17) & 127;
        atomicAdd(&h[key], 1);
        atomicAdd(&dw[key], __int_as_float(q.y));
    }
    __syncthreads();
    if (tid < 64) {
        int lane = tid;
        int carry = 0;
#pragma unroll
        for (int c = 0; c < 2; ++c) {
            int idx = c * 64 + lane;
            int hv = h[idx];
            int v = hv;
#pragma unroll
            for (int off = 1; off < 64; off <<= 1) {
                int t = __shfl_up(v, off, 64);
                if (lane >= off) v += t;
            }
            cur[idx] = base + carry + v - hv;           // start cursor
            int node = b * 128 + idx;
            if (node < NN) {
                rowptr[node] = base + carry + v;        // end offset
                dinv[node] = rsqrtf(1.0f + dw[idx]);    // self-loop included
            }
            carry += __shfl(v, 63, 64);
        }
    }
    __syncthreads();
    for (int i = tid; i < n; i += 512) {
        int2 q = staged ? ed[i] : tre[base + i];
        int key = (q.x >> 17) & 127;
        int pos = atomicAdd(&cur[key], 1);
        unsigned int wb = (unsigned)q.y;                // positive ew bits
        wb += 0x7FFFu + ((wb >> 16) & 1u);              // RNE to bf16
        srn4[pos] = (unsigned)(q.x & SRCMASK) | (((wb >> 16) & 0x7FFFu) << 17);
    }
}

// LDS-tiled linear (layer 1 only): 64-row x tile; W pre-swizzled; thread =
// 2 rows x 4 contiguous cols; output = fp8(dinv[row] * acc).
template <int IN_DIM, bool RELU_IN>
__global__ __launch_bounds__(256)
void linear_k(const float* __restrict__ in, const float* __restrict__ W,
              const float* __restrict__ dinv, unsigned int* __restrict__ tmp8) {
    constexpr int J4 = IN_DIM / 4;
    constexpr int XSS = J4 + 1;
    __shared__ float4 xs[64 * XSS];
    __shared__ float4 wp[IN_DIM * 8];
    int tid = threadIdx.x;
    for (int idx = tid; idx < IN_DIM * 8; idx += 256) {
        int j = idx >> 3, kg = idx & 7;
        const float* wr = W + j * 32 + kg * 4;
        wp[idx] = make_float4(wr[0], wr[1], wr[2], wr[3]);
    }
    int rbase = blockIdx.x * 64;
    const float4* in4 = (const float4*)in;
    for (int idx = tid; idx < 64 * J4; idx += 256) {
        int row = idx / J4, j4 = idx % J4;
        int grow = rbase + row;
        float4 v = (grow < NN) ? in4[(size_t)grow * J4 + j4]
                               : make_float4(0.f, 0.f, 0.f, 0.f);
        if (RELU_IN) {
            v.x = fmaxf(v.x, 0.f); v.y = fmaxf(v.y, 0.f);
            v.z = fmaxf(v.z, 0.f); v.w = fmaxf(v.w, 0.f);
        }
        xs[row * XSS + j4] = v;
    }
    __syncthreads();
    int kg = tid & 7;
    int rp = tid >> 3;
    int r0 = rbase + 2 * rp;
    if (r0 >= NN) return;
    const float4* x0 = &xs[(2 * rp) * XSS];
    const float4* x1 = &xs[(2 * rp + 1) * XSS];
    float a00 = 0, a01 = 0, a02 = 0, a03 = 0;
    float a10 = 0, a11 = 0, a12 = 0, a13 = 0;
#pragma unroll
    for (int j4 = 0; j4 < J4; ++j4) {
        float4 v0 = x0[j4], v1 = x1[j4];
        const float4* wj = &wp[j4 * 4 * 8 + kg];
        float4 w0 = wj[0], w1 = wj[8], w2 = wj[16], w3 = wj[24];
#define LSTEP(VX0, VX1, W4) \
        a00 = fmaf(VX0, W4.x, a00); a01 = fmaf(VX0, W4.y, a01); \
        a02 = fmaf(VX0, W4.z, a02); a03 = fmaf(VX0, W4.w, a03); \
        a10 = fmaf(VX1, W4.x, a10); a11 = fmaf(VX1, W4.y, a11); \
        a12 = fmaf(VX1, W4.z, a12); a13 = fmaf(VX1, W4.w, a13);
        LSTEP(v0.x, v1.x, w0)
        LSTEP(v0.y, v1.y, w1)
        LSTEP(v0.z, v1.z, w2)
        LSTEP(v0.w, v1.w, w3)
#undef LSTEP
    }
    float d0 = dinv[r0], d1 = dinv[r0 + 1];
    a00 *= d0; a01 *= d0; a02 *= d0; a03 *= d0;
    a10 *= d1; a11 *= d1; a12 *= d1; a13 *= d1;
    int q0 = __builtin_amdgcn_cvt_pk_fp8_f32(a00, a01, 0, false);
    q0 = __builtin_amdgcn_cvt_pk_fp8_f32(a02, a03, q0, true);
    int q1 = __builtin_amdgcn_cvt_pk_fp8_f32(a10, a11, 0, false);
    q1 = __builtin_amdgcn_cvt_pk_fp8_f32(a12, a13, q1, true);
    tmp8[r0 * 8 + kg] = (unsigned int)q0;
    tmp8[(r0 + 1) * 8 + kg] = (unsigned int)q1;
}

// gather core v4 (PROVEN R9, 40.4us): FOUR nodes per wave, MASKED BURST.
// lane = n*16 + s*2 + c. All 4 srn4 loads issue in parallel with indices
// clamped to end-1; out-of-range slots get weight 0.
struct AccR { floatx2 r0, r1, r2, r3, r4, r5, r6, r7; };

#define ACC8(A0,A1,A2,A3,A4,A5,A6,A7, U, W) { \
    floatx2 lo_, hi_; \
    lo_ = __builtin_amdgcn_cvt_pk_f32_fp8(U.x, false); \
    hi_ = __builtin_amdgcn_cvt_pk_f32_fp8(U.x, true); \
    A0 += lo_ * W; A1 += hi_ * W; \
    lo_ = __builtin_amdgcn_cvt_pk_f32_fp8(U.y, false); \
    hi_ = __builtin_amdgcn_cvt_pk_f32_fp8(U.y, true); \
    A2 += lo_ * W; A3 += hi_ * W; \
    lo_ = __builtin_amdgcn_cvt_pk_f32_fp8(U.z, false); \
    hi_ = __builtin_amdgcn_cvt_pk_f32_fp8(U.z, true); \
    A4 += lo_ * W; A5 += hi_ * W; \
    lo_ = __builtin_amdgcn_cvt_pk_f32_fp8(U.w, false); \
    hi_ = __builtin_amdgcn_cvt_pk_f32_fp8(U.w, true); \
    A6 += lo_ * W; A7 += hi_ * W; }

__device__ __forceinline__ AccR agg_core(const unsigned int* __restrict__ srn4,
                                         const int* __restrict__ rowptr,
                                         const unsigned int* __restrict__ tmp8,
                                         int nid, int s, unsigned int cb) {
    const char* t8 = (const char*)tmp8;
    int end = rowptr[nid];
    int start = (nid == 0) ? 0 : rowptr[nid - 1];
    floatx2 a0 = {0.f,0.f}, a1 = {0.f,0.f}, a2 = {0.f,0.f}, a3 = {0.f,0.f};
    floatx2 a4 = {0.f,0.f}, a5 = {0.f,0.f}, a6 = {0.f,0.f}, a7 = {0.f,0.f};
    floatx2 b0 = {0.f,0.f}, b1 = {0.f,0.f}, b2 = {0.f,0.f}, b3 = {0.f,0.f};
    floatx2 b4 = {0.f,0.f}, b5 = {0.f,0.f}, b6 = {0.f,0.f}, b7 = {0.f,0.f};
    int eM = end - 1;
    for (int e = start + s; e < end; e += 32) {
        int i1 = min(e + 8, eM);
        int i2 = min(e + 16, eM);
        int i3 = min(e + 24, eM);
        unsigned int p0 = srn4[e];
        unsigned int p1 = srn4[i1];
        unsigned int p2 = srn4[i2];
        unsigned int p3 = srn4[i3];
        uint4 u0 = *(const uint4*)(t8 + (((p0 & SRCMASK) << 5) | cb));
        uint4 u1 = *(const uint4*)(t8 + (((p1 & SRCMASK) << 5) | cb));
        uint4 u2 = *(const uint4*)(t8 + (((p2 & SRCMASK) << 5) | cb));
        uint4 u3 = *(const uint4*)(t8 + (((p3 & SRCMASK) << 5) | cb));
        float w0 = __uint_as_float((p0 >> 1) & 0x7FFF0000u);
        float w1 = (e + 8  <= eM) ? __uint_as_float((p1 >> 1) & 0x7FFF0000u) : 0.f;
        float w2 = (e + 16 <= eM) ? __uint_as_float((p2 >> 1) & 0x7FFF0000u) : 0.f;
        float w3 = (e + 24 <= eM) ? __uint_as_float((p3 >> 1) & 0x7FFF0000u) : 0.f;
        ACC8(a0,a1,a2,a3,a4,a5,a6,a7, u0, w0)
        ACC8(b0,b1,b2,b3,b4,b5,b6,b7, u1, w1)
        ACC8(a0,a1,a2,a3,a4,a5,a6,a7, u2, w2)
        ACC8(b0,b1,b2,b3,b4,b5,b6,b7, u3, w3)
    }
    a0 += b0; a1 += b1; a2 += b2; a3 += b3;
    a4 += b4; a5 += b5; a6 += b6; a7 += b7;
    // reduce across the 8 slots: lane bits 1..3 (masks 2,4,8)
#define REDM(M) { \
    a0.x += __shfl_xor(a0.x, M, 64); a0.y += __shfl_xor(a0.y, M, 64); \
    a1.x += __shfl_xor(a1.x, M, 64); a1.y += __shfl_xor(a1.y, M, 64); \
    a2.x += __shfl_xor(a2.x, M, 64); a2.y += __shfl_xor(a2.y, M, 64); \
    a3.x += __shfl_xor(a3.x, M, 64); a3.y += __shfl_xor(a3.y, M, 64); \
    a4.x += __shfl_xor(a4.x, M, 64); a4.y += __shfl_xor(a4.y, M, 64); \
    a5.x += __shfl_xor(a5.x, M, 64); a5.y += __shfl_xor(a5.y, M, 64); \
    a6.x += __shfl_xor(a6.x, M, 64); a6.y += __shfl_xor(a6.y, M, 64); \
    a7.x += __shfl_xor(a7.x, M, 64); a7.y += __shfl_xor(a7.y, M, 64); }
    REDM(2) REDM(4) REDM(8)
#undef REDM
    AccR r;
    r.r0 = a0; r.r1 = a1; r.r2 = a2; r.r3 = a3;
    r.r4 = a4; r.r5 = a5; r.r6 = a6; r.r7 = a7;
    return r;
}

// self-loop + bias epilogue: lane (c) produces 16 feats as 4 float4s.
#define EPILOGUE16(O0,O1,O2,O3, NID, CB, D, BIAS, A, RELU) { \
    const char* t8_ = (const char*)tmp8; \
    uint4 sv_ = *(const uint4*)(t8_ + (((unsigned)(NID)) << 5) + (CB)); \
    floatx2 s0_ = __builtin_amdgcn_cvt_pk_f32_fp8(sv_.x, false); \
    floatx2 s1_ = __builtin_amdgcn_cvt_pk_f32_fp8(sv_.x, true); \
    floatx2 s2_ = __builtin_amdgcn_cvt_pk_f32_fp8(sv_.y, false); \
    floatx2 s3_ = __builtin_amdgcn_cvt_pk_f32_fp8(sv_.y, true); \
    floatx2 s4_ = __builtin_amdgcn_cvt_pk_f32_fp8(sv_.z, false); \
    floatx2 s5_ = __builtin_amdgcn_cvt_pk_f32_fp8(sv_.z, true); \
    floatx2 s6_ = __builtin_amdgcn_cvt_pk_f32_fp8(sv_.w, false); \
    floatx2 s7_ = __builtin_amdgcn_cvt_pk_f32_fp8(sv_.w, true); \
    const float4* bp_ = (const float4*)(BIAS) + 4 * c; \
    float4 bq0_ = bp_[0], bq1_ = bp_[1], bq2_ = bp_[2], bq3_ = bp_[3]; \
    O0.x = bq0_.x + (D) * (s0_.x + A.r0.x); \
    O0.y = bq0_.y + (D) * (s0_.y + A.r0.y); \
    O0.z = bq0_.z + (D) * (s1_.x + A.r1.x); \
    O0.w = bq0_.w + (D) * (s1_.y + A.r1.y); \
    O1.x = bq1_.x + (D) * (s2_.x + A.r2.x); \
    O1.y = bq1_.y + (D) * (s2_.y + A.r2.y); \
    O1.z = bq1_.z + (D) * (s3_.x + A.r3.x); \
    O1.w = bq1_.w + (D) * (s3_.y + A.r3.y); \
    O2.x = bq2_.x + (D) * (s4_.x + A.r4.x); \
    O2.y = bq2_.y + (D) * (s4_.y + A.r4.y); \
    O2.z = bq2_.z + (D) * (s5_.x + A.r5.x); \
    O2.w = bq2_.w + (D) * (s5_.y + A.r5.y); \
    O3.x = bq3_.x + (D) * (s6_.x + A.r6.x); \
    O3.y = bq3_.y + (D) * (s6_.y + A.r6.y); \
    O3.z = bq3_.z + (D) * (s7_.x + A.r7.x); \
    O3.w = bq3_.w + (D) * (s7_.y + A.r7.y); \
    if (RELU) { \
        O0.x = fmaxf(O0.x, 0.f); O0.y = fmaxf(O0.y, 0.f); \
        O0.z = fmaxf(O0.z, 0.f); O0.w = fmaxf(O0.w, 0.f); \
        O1.x = fmaxf(O1.x, 0.f); O1.y = fmaxf(O1.y, 0.f); \
        O1.z = fmaxf(O1.z, 0.f); O1.w = fmaxf(O1.w, 0.f); \
        O2.x = fmaxf(O2.x, 0.f); O2.y = fmaxf(O2.y, 0.f); \
        O2.z = fmaxf(O2.z, 0.f); O2.w = fmaxf(O2.w, 0.f); \
        O3.x = fmaxf(O3.x, 0.f); O3.y = fmaxf(O3.y, 0.f); \
        O3.z = fmaxf(O3.z, 0.f); O3.w = fmaxf(O3.w, 0.f); \
    } }

// plain aggregate (layer 3): writes fp32 h for pooling (no relu).
// 4 nodes per wave: 6250 blocks x 16 nodes. No barrier.
__global__ __launch_bounds__(256)
void aggregate(const unsigned int* __restrict__ srn4,
               const int* __restrict__ rowptr,
               const float* __restrict__ dinv,
               const float* __restrict__ bias,
               const unsigned int* __restrict__ tmp8,
               float* __restrict__ h) {
    int tid = threadIdx.x;
    int nid = (blockIdx.x * 256 + tid) >> 4;   // 6250*16 == NN exactly
    int lane = tid & 63;
    int c = lane & 1, s = (lane >> 1) & 7;
    unsigned int cb = (unsigned int)c * 16u;
    AccR A = agg_core(srn4, rowptr, tmp8, nid, s, cb);
    if ((lane & 14) == 0) {                    // s == 0 lanes: 2 per node
        float d = dinv[nid];
        float4 o0, o1, o2, o3;
        EPILOGUE16(o0, o1, o2, o3, nid, cb, d, bias, A, false)
        float4* hp = (float4*)(h + (size_t)nid * HID + 16 * c);
        hp[0] = o0; hp[1] = o1; hp[2] = o2; hp[3] = o3;
    }
}

// fused aggregate + relu + 32x32 next-layer linear + fp8 store (layers 1->2,
// 2->3). 4 nodes per wave; W staged transposed+padded in LDS.
__global__ __launch_bounds__(256)
void agg_lin(const unsigned int* __restrict__ srn4,
             const int* __restrict__ rowptr,
             const float* __restrict__ dinv,
             const float* __restrict__ bias,
             const float* __restrict__ Wn,
             const unsigned int* __restrict__ tmp8,
             unsigned int* __restrict__ tmp8_out) {
    __shared__ float hrow[4][4][HID];          // 2 KB
    __shared__ float Wt[32][36];               // 4.6 KB, transposed W
    int tid = threadIdx.x;
    for (int idx = tid; idx < 1024; idx += 256)
        Wt[idx & 31][idx >> 5] = Wn[idx];      // Wt[j][k] = Wn[k*32+j]
    int nid = (blockIdx.x * 256 + tid) >> 4;   // 6250*16 == NN exactly
    int wv = tid >> 6;
    int lane = tid & 63;
    int n = (lane >> 4) & 3;
    int c = lane & 1, s = (lane >> 1) & 7;
    unsigned int cb = (unsigned int)c * 16u;
    __syncthreads();                           // Wt ready (uniform)
    AccR A = agg_core(srn4, rowptr, tmp8, nid, s, cb);
    float d = dinv[nid];
    if ((lane & 14) == 0) {                    // s == 0 lanes: 2 per node
        float4 o0, o1, o2, o3;
        EPILOGUE16(o0, o1, o2, o3, nid, cb, d, bias, A, true)
        float4* hp = (float4*)&hrow[wv][n][16 * c];
        hp[0] = o0; hp[1] = o1; hp[2] = o2; hp[3] = o3;
    }
    // matvec: 16 lanes per node, lane computes outputs j0 and j0+16.
    int j0 = lane & 15;
    const float4* hb = (const float4*)&hrow[wv][n][0];
    float4 h0 = hb[0], h1 = hb[1], h2 = hb[2], h3 = hb[3];
    float4 h4 = hb[4], h5 = hb[5], h6 = hb[6], h7 = hb[7];
    const float4* w0p = (const float4*)&Wt[j0][0];
    const float4* w1p = (const float4*)&Wt[j0 + 16][0];
    float y0 = 0.f, y1 = 0.f;
#define MVSTEP(K, HV) { float4 wa_ = w0p[K]; float4 wb_ = w1p[K]; \
    y0 = fmaf(HV.x, wa_.x, y0); y0 = fmaf(HV.y, wa_.y, y0); \
    y0 = fmaf(HV.z, wa_.z, y0); y0 = fmaf(HV.w, wa_.w, y0); \
    y1 = fmaf(HV.x, wb_.x, y1); y1 = fmaf(HV.y, wb_.y, y1); \
    y1 = fmaf(HV.z, wb_.z, y1); y1 = fmaf(HV.w, wb_.w, y1); }
    MVSTEP(0, h0) MVSTEP(1, h1) MVSTEP(2, h2) MVSTEP(3, h3)
    MVSTEP(4, h4) MVSTEP(5, h5) MVSTEP(6, h6) MVSTEP(7, h7)
#undef MVSTEP
    y0 *= d; y1 *= d;
    float p1 = __shfl_down(y0, 1, 64);
    float p2 = __shfl_down(y0, 2, 64);
    float p3 = __shfl_down(y0, 3, 64);
    float q1 = __shfl_down(y1, 1, 64);
    float q2 = __shfl_down(y1, 2, 64);
    float q3 = __shfl_down(y1, 3, 64);
    if ((j0 & 3) == 0) {
        int t = j0 >> 2;
        int w0 = __builtin_amdgcn_cvt_pk_fp8_f32(y0, p1, 0, false);
        w0 = __builtin_amdgcn_cvt_pk_fp8_f32(p2, p3, w0, true);
        int w1 = __builtin_amdgcn_cvt_pk_fp8_f32(y1, q1, 0, false);
        w1 = __builtin_amdgcn_cvt_pk_fp8_f32(q2, q3, w1, true);
        tmp8_out[nid * 8 + t] = (unsigned int)w0;
        tmp8_out[nid * 8 + 4 + t] = (unsigned int)w1;
    }
}

// sorted-batch run-length pooling (3125 chunks x 32 nodes, boundary atomics)
__global__ void pool_k(const float* __restrict__ h, const int* __restrict__ batch,
                       float* __restrict__ sums, float* __restrict__ counts) {
    int t = blockIdx.x * 256 + threadIdx.x;
    int chunk = t >> 5, k = t & 31;
    int n0 = chunk * 32;
    if (n0 >= NN) return;
    int n1 = min(n0 + 32, NN);
    int g = batch[n0];
    float acc = 0.f, cacc = 0.f;
    for (int i = n0; i < n1; ++i) {
        int gi = batch[i];
        if (gi != g) {
            atomicAdd(&sums[g * HID + k], acc);
            if (k == 0) atomicAdd(&counts[g], cacc);
            g = gi; acc = 0.f; cacc = 0.f;
        }
        acc += h[(size_t)i * HID + k];
        cacc += 1.f;
    }
    atomicAdd(&sums[g * HID + k], acc);
    if (k == 0) atomicAdd(&counts[g], cacc);
}

// MLP: one block per graph, one wave; thread k owns output column k.
__global__ __launch_bounds__(64)
void mlp_k(const float* __restrict__ sums, const float* __restrict__ counts,
           const float* __restrict__ Wm0, const float* __restrict__ bm0,
           const float* __restrict__ Wm1, const float* __restrict__ bm1,
           const float* __restrict__ Wout, const float* __restrict__ bout,
           float* __restrict__ out) {
    __shared__ float g0[HID];
    __shared__ float g1[MH];
    __shared__ float g2[MH];
    int g = blockIdx.x;
    int k = threadIdx.x;
    if (k < HID) g0[k] = sums[g * HID + k] / fmaxf(counts[g], 1.0f);
    __syncthreads();
    float acc = bm0[k];
#pragma unroll
    for (int j = 0; j < HID; ++j) acc = fmaf(g0[j], Wm0[j * MH + k], acc);
    g1[k] = fmaxf(acc, 0.f);
    __syncthreads();
    float acc2 = bm1[k];
#pragma unroll
    for (int j = 0; j < MH; ++j) acc2 = fmaf(g1[j], Wm1[j * MH + k], acc2);
    g2[k] = fmaxf(acc2, 0.f);
    __syncthreads();
    if (k < NC) {
        float acc3 = bout[k];
#pragma unroll
        for (int j = 0; j < MH; ++j) acc3 = fmaf(g2[j], Wout[j * NC + k], acc3);
        out[g * NC + k] = acc3;
    }
}

extern "C" void kernel_launch(void* const* d_in, const int* in_sizes, int n_in,
                              void* d_out, int out_size, void* d_ws, size_t ws_size,
                              hipStream_t stream) {
    const float* x    = (const float*)d_in[0];
    const int*   ei   = (const int*)d_in[1];
    const float* ew   = (const float*)d_in[2];
    const int*   batch= (const int*)d_in[3];
    const float* W1   = (const float*)d_in[4];
    const float* b1   = (const float*)d_in[5];
    const float* W2   = (const float*)d_in[6];
    const float* b2   = (const float*)d_in[7];
    const float* W3   = (const float*)d_in[8];
    const float* b3   = (const float*)d_in[9];
    const float* Wm0  = (const float*)d_in[10];
    const float* bm0  = (const float*)d_in[11];
    const float* Wm1  = (const float*)d_in[12];
    const float* bm1  = (const float*)d_in[13];
    const float* Wout = (const float*)d_in[14];
    const float* bout = (const float*)d_in[15];
    float* out = (float*)d_out;

    // workspace: srn4 | S (tre+cnt2+scanned <-> tmp8+tmp8b+hA) | small bufs
    char* p = (char*)d_ws;
    unsigned int* srn4 = (unsigned int*)p; p += sizeof(unsigned int) * (size_t)NE; // 12.8 MB
    char*  S   = p;                      p += 12 * (size_t)NE;                // 38.4 MB shared
    int2*  tre = (int2*)S;                                                    // 25.6 MB
    int*   cnt2    = (int*)(S + sizeof(int2) * (size_t)NE);                   // 1.6 MB (dies pre-layer1)
    int*   scanned = cnt2 + SCANL;                                            // 1.6 MB
    unsigned int* tmp8  = (unsigned int*)S;                                   // 3.2 MB
    unsigned int* tmp8b = tmp8 + (size_t)NN * 8;                              // 3.2 MB
    float* hA  = (float*)(S + 2 * (size_t)NN * HID);                          // 12.8 MB
    int*   bsum    = (int*)p;            p += sizeof(int) * 512;
    float* dinv    = (float*)p;          p += sizeof(float) * NN;
    int*   rowptr  = (int*)p;            p += sizeof(int) * NN;
    float* sums    = (float*)p;          p += sizeof(float) * NG * HID;
    float* counts  = (float*)p;

    dim3 blk(256);
    const int NB_SCAN = (SCANL + 1023) / 1024;  // 391
    const int NB_LIN = (NN + 63) / 64;          // 1563
    const int NB_AGG = 6250;                    // 16 nodes per block (4/wave)

    hist_bkt<<<NBLK, 1024, 0, stream>>>(ei, cnt2);
    scan_cnt<<<NB_SCAN, blk, 0, stream>>>(cnt2, scanned, bsum);
    scan_top<<<1, 64, 0, stream>>>(bsum, NB_SCAN, sums);  // also zeroes sums+counts
    scatter_bkt<<<NBLK, 1024, 0, stream>>>(ei, ew, cnt2, scanned, bsum, tre);
    sort_k<<<NBKT, 512, 0, stream>>>(tre, scanned, bsum, srn4, rowptr, dinv);

    // layer 1 linear, then fused agg1+linear2, fused agg2+linear3, plain agg3
    linear_k<FIN, false><<<NB_LIN, blk, 0, stream>>>(x, W1, dinv, tmp8);
    agg_lin<<<NB_AGG, blk, 0, stream>>>(srn4, rowptr, dinv, b1, W2, tmp8, tmp8b);
    agg_lin<<<NB_AGG, blk, 0, stream>>>(srn4, rowptr, dinv, b2, W3, tmp8b, tmp8);
    aggregate<<<NB_AGG, blk, 0, stream>>>(srn4, rowptr, dinv, b3, tmp8, hA);

    pool_k<<<391, blk, 0, stream>>>(hA, batch, sums, counts);
    mlp_k<<<NG, 64, 0, stream>>>(sums, counts, Wm0, bm0, Wm1, bm1, Wout, bout, out);
}